// Round 9
// baseline (285.088 us; speedup 1.0000x reference)
//
#include <hip/hip_runtime.h>
#include <hip/hip_bf16.h>

typedef unsigned short u16;
typedef unsigned int u32;
typedef __attribute__((ext_vector_type(8))) short short8x;   // 8 bf16 (4 VGPR)
typedef __attribute__((ext_vector_type(4))) float f32x4;

__device__ __forceinline__ u16 bf16u(float x) {
    __hip_bfloat16 h = __float2bfloat16(x);
    return *reinterpret_cast<u16*>(&h);
}

__device__ __forceinline__ void gload_lds16(const void* g, void* l) {
    __builtin_amdgcn_global_load_lds(
        (const __attribute__((address_space(1))) u32*)g,
        (__attribute__((address_space(3))) u32*)l, 16, 0, 0);
}

// m=64, n=1024, W=H=512
#define M_  64
#define N_  1024
#define W_  512
#define SP_ROW 163840   // packed S' row length per i: 10 tiles * 16384

// ---------------------------------------------------------------------------
// P0 (grid 1040): blocks 0..1023: invs[i][n] = 1/max(||psi[i][n]||,eps).
// No LDS in this path -> high occupancy, pure BW. blocks 1024..1039: phi-gram
// g2[i][j] (f32, exact); gb==0 seeds out[0] = -m*n for K3's atomics.
// ---------------------------------------------------------------------------
__global__ __launch_bounds__(256) void p0_norms(const float* __restrict__ psi,
                                                const float* __restrict__ phi,
                                                float* __restrict__ invs,
                                                float* __restrict__ g2,
                                                float* __restrict__ out) {
    const int t = threadIdx.x;
    __shared__ float pis[2048];
    __shared__ float djs[4][64], nsqs[64];

    if (blockIdx.x < 1024) {
        const int i  = blockIdx.x >> 4;
        const int nb = blockIdx.x & 15;
        const int sub = t & 15;             // 16 threads per row
        const float* base = psi + ((size_t)i * N_ + (size_t)nb * 64) * W_;
#pragma unroll
        for (int pp = 0; pp < 4; ++pp) {
            const int r = pp * 16 + (t >> 4);
            const float4* rb = (const float4*)(base + (size_t)r * W_) + sub;
            float s = 0.f;
#pragma unroll
            for (int k = 0; k < 8; ++k) {
                float4 v = rb[k * 16];
                s += v.x * v.x + v.y * v.y + v.z * v.z + v.w * v.w;
            }
#pragma unroll
            for (int o = 1; o < 16; o <<= 1) s += __shfl_xor(s, o);
            if (sub == 0)
                invs[i * N_ + nb * 64 + r] = 1.0f / fmaxf(sqrtf(s), 1e-12f);
        }
    } else {
        const int gb = blockIdx.x - 1024;   // 0..15
        const int i0 = gb * 4;
        const int lane = t & 63, wv = t >> 6;
#pragma unroll
        for (int r = 0; r < 4; ++r) {
            pis[r * 512 + t]       = phi[(i0 + r) * 512 + t];
            pis[r * 512 + 256 + t] = phi[(i0 + r) * 512 + 256 + t];
        }
        __syncthreads();
        for (int jj = 0; jj < 16; ++jj) {
            int j = wv + jj * 4;
            const float* pj = phi + j * 512;
            float nn = 0.f, d0 = 0.f, d1 = 0.f, d2 = 0.f, d3 = 0.f;
#pragma unroll
            for (int e = 0; e < 8; ++e) {
                float x = pj[lane + e * 64];
                nn += x * x;
                d0 += pis[0 * 512 + lane + e * 64] * x;
                d1 += pis[1 * 512 + lane + e * 64] * x;
                d2 += pis[2 * 512 + lane + e * 64] * x;
                d3 += pis[3 * 512 + lane + e * 64] * x;
            }
#pragma unroll
            for (int o = 32; o; o >>= 1) {
                nn += __shfl_xor(nn, o);
                d0 += __shfl_xor(d0, o);
                d1 += __shfl_xor(d1, o);
                d2 += __shfl_xor(d2, o);
                d3 += __shfl_xor(d3, o);
            }
            if (lane == 0) {
                djs[0][j] = d0; djs[1][j] = d1; djs[2][j] = d2; djs[3][j] = d3;
                nsqs[j] = nn;
            }
        }
        __syncthreads();
        if (t < 64) {
            const int j = t;
            const float invj = 1.0f / fmaxf(sqrtf(nsqs[j]), 1e-12f);
#pragma unroll
            for (int r = 0; r < 4; ++r) {
                const float invi = 1.0f / fmaxf(sqrtf(nsqs[i0 + r]), 1e-12f);
                const float g = djs[r][j] * invi * invj;
                g2[(i0 + r) * 64 + j] = g * g;
            }
        }
        if (gb == 0 && t == 0) out[0] = -65536.0f;
    }
}

// ---------------------------------------------------------------------------
// P1 (grid 512): block = (i = bid>>3, w-chunk of 64). Reads psi[n][wchunk]
// (L3-warm after P0), scales by invs, transposes via w-major LDS tile,
// writes psiT[i][w][n] rows CONTIGUOUSLY (256B/instr).
// LDS tile u16[64][258]: write banks 129*(4sub+j)+n/2 -> all-distinct;
// read banks 129*w+c -> all-distinct. 38KB LDS -> 4 blocks/CU.
// ---------------------------------------------------------------------------
__global__ __launch_bounds__(256) void p1_transpose(const float* __restrict__ psi,
                                                    const float* __restrict__ invs,
                                                    u16* __restrict__ psiT) {
    const int t  = threadIdx.x;
    const int i  = blockIdx.x >> 3;
    const int wc = blockIdx.x & 7;
    const int w0 = wc * 64;

    __shared__ u16   tile[64][258];     // [w][n-slab], pitch 258 u16
    __shared__ float invl[1024];

    ((float4*)invl)[t] = ((const float4*)(invs + (size_t)i * N_))[t];

    const int sub = t & 15;             // lane-in-row (w quad)
    const int rr  = t >> 4;             // row-in-round
    const float* base = psi + (size_t)i * N_ * W_ + w0;
    u32* out32 = (u32*)psiT + (size_t)i * (W_ * N_ / 2);
    const int lane = t & 63, wv = t >> 6;

    for (int s = 0; s < 4; ++s) {
        const int nbase = s * 256;
        __syncthreads();                 // tile reuse + invl ready (s=0)
#pragma unroll
        for (int rnd = 0; rnd < 16; ++rnd) {
            const int n = rnd * 16 + rr;
            float4 v = *(const float4*)(base + (size_t)(nbase + n) * W_ + sub * 4);
            const float inv = invl[nbase + n];
            const int wl = sub * 4;
            tile[wl + 0][n] = bf16u(v.x * inv);
            tile[wl + 1][n] = bf16u(v.y * inv);
            tile[wl + 2][n] = bf16u(v.z * inv);
            tile[wl + 3][n] = bf16u(v.w * inv);
        }
        __syncthreads();
#pragma unroll
        for (int ww = 0; ww < 16; ++ww) {
            const int w = wv * 16 + ww;
#pragma unroll
            for (int h = 0; h < 2; ++h) {
                const int c = h * 64 + lane;          // u32 col within slab
                u32 val = *(const u32*)&tile[w][2 * c];
                out32[(size_t)(w0 + w) * 512 + (nbase >> 1) + c] = val;
            }
        }
    }
}

// ---------------------------------------------------------------------------
// K2: batched SYRK  S_i = psiT_i * psiT_i^T, upper-triangle 128x128 tiles only.
// grid 640 flat, XCD-swizzled. block 256 (2x2 waves), BK=64, 16 K-iters,
// T3-min double-buffer, source-side XOR-swizzled LDS. Output packed with
// sqrt(2) off-diag scale so b[i][j] = <Sp_i, Sp_j> exactly.
// ---------------------------------------------------------------------------
__global__ __launch_bounds__(256) void syrk_bf16(const u16* __restrict__ psiT,
                                                 u16* __restrict__ Sp) {
    const int L = blockIdx.x;
    const int q = L >> 3;
    const int i  = (L & 7) * 8 + q / 10;
    const int bt = q % 10;
    int tr, tc;
    if      (bt < 4) { tr = 0; tc = bt;     }
    else if (bt < 7) { tr = 1; tc = bt - 3; }
    else if (bt < 9) { tr = 2; tc = bt - 5; }
    else             { tr = 3; tc = 3;      }
    const int t = threadIdx.x;

    const u16* Abase = psiT + (size_t)i * W_ * N_ + (size_t)tr * 128 * N_;
    const u16* Bbase = psiT + (size_t)i * W_ * N_ + (size_t)tc * 128 * N_;

    __shared__ alignas(16) u16 ldsA[2][128][64];   // 2 x 16 KB
    __shared__ alignas(16) u16 ldsB[2][128][64];

    const int lane = t & 63, wv = t >> 6;
    const int wr = wv >> 1, wc = wv & 1;
    const int lrow = lane & 15, lk8 = lane >> 4;

    auto STAGE = [&](int buf, int kt) {
        const int k0 = kt * 64;
#pragma unroll
        for (int r = 0; r < 4; ++r) {
            int c = r * 256 + t;
            int row = c >> 3, cch = c & 7;
            int scch = cch ^ (row & 7);            // pre-swizzled source chunk
            gload_lds16(Abase + (size_t)row * N_ + k0 + scch * 8, &ldsA[buf][row][cch * 8]);
            gload_lds16(Bbase + (size_t)row * N_ + k0 + scch * 8, &ldsB[buf][row][cch * 8]);
        }
    };

    f32x4 acc[4][4];
#pragma unroll
    for (int a = 0; a < 4; ++a)
#pragma unroll
        for (int b = 0; b < 4; ++b) acc[a][b] = (f32x4){0.f, 0.f, 0.f, 0.f};

    STAGE(0, 0);
    asm volatile("s_waitcnt vmcnt(0)" ::: "memory");
    __builtin_amdgcn_s_barrier();

    int cur = 0;
    for (int kt = 0; kt < 16; ++kt) {
        if (kt < 15) STAGE(cur ^ 1, kt + 1);       // issue next-tile loads early
#pragma unroll
        for (int ks = 0; ks < 2; ++ks) {
            short8x af[4], bf[4];
#pragma unroll
            for (int mf = 0; mf < 4; ++mf) {
                int row = wr * 64 + mf * 16 + lrow;
                int ch = (ks * 4 + lk8) ^ (row & 7);
                af[mf] = *(const short8x*)&ldsA[cur][row][ch * 8];
            }
#pragma unroll
            for (int nf = 0; nf < 4; ++nf) {
                int row = wc * 64 + nf * 16 + lrow;
                int ch = (ks * 4 + lk8) ^ (row & 7);
                bf[nf] = *(const short8x*)&ldsB[cur][row][ch * 8];
            }
#pragma unroll
            for (int mf = 0; mf < 4; ++mf)
#pragma unroll
                for (int nf = 0; nf < 4; ++nf)
                    acc[mf][nf] = __builtin_amdgcn_mfma_f32_16x16x32_bf16(
                        af[mf], bf[nf], acc[mf][nf], 0, 0, 0);
        }
        asm volatile("s_waitcnt vmcnt(0)" ::: "memory");
        __builtin_amdgcn_sched_barrier(0);
        __builtin_amdgcn_s_barrier();
        cur ^= 1;
    }

    const float sc = (tr == tc) ? 1.0f : 1.41421356237f;
    size_t Sbase = (size_t)i * SP_ROW + (size_t)bt * 16384;
#pragma unroll
    for (int mf = 0; mf < 4; ++mf)
#pragma unroll
        for (int nf = 0; nf < 4; ++nf)
#pragma unroll
            for (int reg = 0; reg < 4; ++reg) {
                int wl = wr * 64 + mf * 16 + lk8 * 4 + reg;
                int vl = wc * 64 + nf * 16 + lrow;
                Sp[Sbase + (size_t)wl * 128 + vl] = bf16u(acc[mf][nf][reg] * sc);
            }
}

// ---------------------------------------------------------------------------
// K3: weighted split-K: partial = Sp * Sp^T over a 256-elem K-chunk, weight
// by g2 in-register, ONE atomicAdd per block into out. grid 640, block 256.
// ---------------------------------------------------------------------------
__global__ __launch_bounds__(256) void bgemm_w(const u16* __restrict__ Sp,
                                               const float* __restrict__ g2,
                                               float* __restrict__ out) {
    const int t = threadIdx.x;
    const int lane = t & 63, wv = t >> 6;
    const int wr = wv >> 1, wc = wv & 1;
    const int lrow = lane & 15, lk8 = lane >> 4;
    const size_t kc0 = (size_t)blockIdx.x * 256;

    f32x4 acc[2][2];
#pragma unroll
    for (int a = 0; a < 2; ++a)
#pragma unroll
        for (int b = 0; b < 2; ++b) acc[a][b] = (f32x4){0.f, 0.f, 0.f, 0.f};

#pragma unroll
    for (int ks = 0; ks < 8; ++ks) {
        short8x af[2], bf[2];
#pragma unroll
        for (int mf = 0; mf < 2; ++mf) {
            int row = wr * 32 + mf * 16 + lrow;
            af[mf] = *(const short8x*)(Sp + (size_t)row * SP_ROW + kc0 + (ks * 4 + lk8) * 8);
        }
#pragma unroll
        for (int nf = 0; nf < 2; ++nf) {
            int row = wc * 32 + nf * 16 + lrow;
            bf[nf] = *(const short8x*)(Sp + (size_t)row * SP_ROW + kc0 + (ks * 4 + lk8) * 8);
        }
#pragma unroll
        for (int mf = 0; mf < 2; ++mf)
#pragma unroll
            for (int nf = 0; nf < 2; ++nf)
                acc[mf][nf] = __builtin_amdgcn_mfma_f32_16x16x32_bf16(
                    af[mf], bf[nf], acc[mf][nf], 0, 0, 0);
    }

    float wsum = 0.f;
#pragma unroll
    for (int mf = 0; mf < 2; ++mf)
#pragma unroll
        for (int nf = 0; nf < 2; ++nf) {
            const int jc = wc * 32 + nf * 16 + lrow;
#pragma unroll
            for (int reg = 0; reg < 4; ++reg) {
                const int ir = wr * 32 + mf * 16 + lk8 * 4 + reg;
                wsum += acc[mf][nf][reg] * g2[ir * 64 + jc];
            }
        }
#pragma unroll
    for (int o = 32; o; o >>= 1) wsum += __shfl_down(wsum, o);
    __shared__ float w4[4];
    if (lane == 0) w4[wv] = wsum;
    __syncthreads();
    if (t == 0) atomicAdd(out, w4[0] + w4[1] + w4[2] + w4[3]);
}

// Fallback marker if workspace is too small (visible-wrong, not OOB-crash).
__global__ void wsfail(float* __restrict__ out) {
    if (threadIdx.x == 0) out[0] = 1.0e30f;
}

extern "C" void kernel_launch(void* const* d_in, const int* in_sizes, int n_in,
                              void* d_out, int out_size, void* d_ws, size_t ws_size,
                              hipStream_t stream) {
    const float* phi = (const float*)d_in[0];
    const float* psi = (const float*)d_in[1];
    float* out = (float*)d_out;
    char* ws = (char*)d_ws;

    // workspace layout (bytes):
    //   [0 .. 64MB)            psiT bf16 [64][512][1024]  (P1 -> K2)
    //   [64MB .. 84MB)         Sp   bf16 [64][163840]     (K2 -> K3)
    //   [84MB .. +16KB)        g2   f32  [64][64]         (P0 -> K3)
    //   [84MB+16KB .. +256KB)  invs f32  [64][1024]       (P0 -> P1)
    const size_t NEEDED = 67108864ull + 20971520ull + 16384ull + 262144ull;
    if (ws_size < NEEDED) {
        wsfail<<<1, 64, 0, stream>>>(out);
        return;
    }
    u16*   psiT = (u16*)(ws);
    u16*   Sp   = (u16*)(ws + 67108864);
    float* g2   = (float*)(ws + 88080384);
    float* invs = (float*)(ws + 88096768);

    p0_norms    <<<1040, 256, 0, stream>>>(psi, phi, invs, g2, out);
    p1_transpose<<<512,  256, 0, stream>>>(psi, invs, psiT);
    syrk_bf16   <<<640,  256, 0, stream>>>(psiT, Sp);
    bgemm_w     <<<640,  256, 0, stream>>>(Sp, g2, out);
}